// Round 1
// baseline (164.214 us; speedup 1.0000x reference)
//
#include <hip/hip_runtime.h>
#include <stdint.h>

#define NSRC 49152
#define NTGT 12288
#define DIM  128
#define BCT  16
#define MPER 8
#define ROWS (MPER*BCT)   // 128 rows per block = 8 targets x 16 bct

using short8 = __attribute__((ext_vector_type(8))) short;
using bf16x8 = __attribute__((ext_vector_type(8))) __bf16;
using f32x4  = __attribute__((ext_vector_type(4))) float;

__device__ __forceinline__ short f2bf(float f){
  unsigned int u = __float_as_uint(f);
  return (short)((u + 0x7fffu + ((u >> 16) & 1u)) >> 16);   // RNE
}

// ---- counting sort of the inverse map ----
__global__ void k_hist(const int* __restrict__ pm, int* __restrict__ counts){
  int i = blockIdx.x * blockDim.x + threadIdx.x;
  if (i < NSRC) atomicAdd(&counts[pm[i]], 1);
}

__global__ void k_scan(const int* __restrict__ counts,
                       int* __restrict__ offsets, int* __restrict__ cursor){
  __shared__ int s[1024];
  const int t = threadIdx.x;
  const int base = t * 12;            // 12288 = 1024*12
  int loc[12]; int sum = 0;
  #pragma unroll
  for (int j = 0; j < 12; ++j){ loc[j] = counts[base + j]; sum += loc[j]; }
  s[t] = sum;
  __syncthreads();
  for (int off = 1; off < 1024; off <<= 1){
    int v = (t >= off) ? s[t - off] : 0;
    __syncthreads();
    s[t] += v;
    __syncthreads();
  }
  int run = s[t] - sum;               // exclusive prefix
  #pragma unroll
  for (int j = 0; j < 12; ++j){
    offsets[base + j] = run;
    cursor [base + j] = run;
    run += loc[j];
  }
}

__global__ void k_scatter(const int* __restrict__ pm,
                          int* __restrict__ cursor, int* __restrict__ child){
  int i = blockIdx.x * blockDim.x + threadIdx.x;
  if (i < NSRC){
    int p = pm[i];
    int pos = atomicAdd(&cursor[p], 1);
    child[pos] = i;
  }
}

// ---- fused pool(mean) + 1x1 conv ----
__global__ __launch_bounds__(256, 2) void k_fused(
    const float* __restrict__ x, const float* __restrict__ W,
    const float* __restrict__ bias,
    const int* __restrict__ counts, const int* __restrict__ offsets,
    const int* __restrict__ child, float* __restrict__ out)
{
  // bf16, XOR-swizzled rows: element (row, col) stored at row*DIM + (col ^ ((row&7)<<3))
  __shared__ __align__(16) short s_wt  [DIM  * DIM];  // W[e][d]  -> MFMA B operand
  __shared__ __align__(16) short s_mean[ROWS * DIM];  // mean[r][d] -> MFMA A operand
  const int tid = threadIdx.x;
  const int m0  = blockIdx.x * MPER;

  // --- stage W (f32 -> bf16, swizzled) ---
  {
    const int q = tid & 3;
    #pragma unroll
    for (int it = 0; it < 2; ++it){
      const int e = it * 64 + (tid >> 2);
      const float4* pw = (const float4*)(W + (size_t)e * DIM + q * 32);
      const int esw = (e & 7) << 3;
      #pragma unroll
      for (int c = 0; c < 4; ++c){
        float4 u = pw[2*c], v = pw[2*c + 1];
        short8 h;
        h[0]=f2bf(u.x); h[1]=f2bf(u.y); h[2]=f2bf(u.z); h[3]=f2bf(u.w);
        h[4]=f2bf(v.x); h[5]=f2bf(v.y); h[6]=f2bf(v.z); h[7]=f2bf(v.w);
        *reinterpret_cast<short8*>(&s_wt[e * DIM + ((q*32 + c*8) ^ esw)]) = h;
      }
    }
  }

  // --- gather children, fp32 mean, write bf16 swizzled ---
  {
    const int q = tid & 3;                 // d-quarter: 32 floats
    #pragma unroll
    for (int it = 0; it < 2; ++it){
      const int r   = it * 64 + (tid >> 2);
      const int m   = m0 + (r >> 4);
      const int bct = r & 15;
      const int cnt = counts[m];
      const int off = offsets[m];
      float4 acc[8];
      #pragma unroll
      for (int j = 0; j < 8; ++j) acc[j] = make_float4(0.f, 0.f, 0.f, 0.f);
      for (int c = 0; c < cnt; ++c){
        const int n = child[off + c];
        const float4* px = (const float4*)(x + ((size_t)bct * NSRC + n) * DIM + q * 32);
        #pragma unroll
        for (int j = 0; j < 8; ++j){
          float4 v = px[j];
          acc[j].x += v.x; acc[j].y += v.y; acc[j].z += v.z; acc[j].w += v.w;
        }
      }
      const float inv = (cnt > 0) ? (1.0f / (float)cnt) : 0.0f; // cnt=0 -> sum=0 -> mean=0
      const int rsw = (r & 7) << 3;
      #pragma unroll
      for (int c = 0; c < 4; ++c){
        float4 u = acc[2*c], v = acc[2*c + 1];
        short8 h;
        h[0]=f2bf(u.x*inv); h[1]=f2bf(u.y*inv); h[2]=f2bf(u.z*inv); h[3]=f2bf(u.w*inv);
        h[4]=f2bf(v.x*inv); h[5]=f2bf(v.y*inv); h[6]=f2bf(v.z*inv); h[7]=f2bf(v.w*inv);
        *reinterpret_cast<short8*>(&s_mean[r * DIM + ((q*32 + c*8) ^ rsw)]) = h;
      }
    }
  }

  __syncthreads();

  // --- MFMA: out[r][e] = sum_d mean[r][d] * W[e][d] + b[e] ---
  {
    const int w  = tid >> 6;          // wave 0..3 -> row block of 32
    const int l  = tid & 63;
    const int lr = l & 15;
    const int lk = (l >> 4) * 8;      // k offset within 32-chunk
    f32x4 acc[2][8];
    #pragma unroll
    for (int i = 0; i < 2; ++i)
      #pragma unroll
      for (int n = 0; n < 8; ++n) acc[i][n] = (f32x4){0.f, 0.f, 0.f, 0.f};

    #pragma unroll
    for (int ks = 0; ks < 4; ++ks){
      const int k = ks * 32 + lk;
      bf16x8 af[2], bfr[8];
      #pragma unroll
      for (int i = 0; i < 2; ++i){
        const int row = w * 32 + i * 16 + lr;
        af[i] = *reinterpret_cast<bf16x8*>(&s_mean[row * DIM + (k ^ ((row & 7) << 3))]);
      }
      #pragma unroll
      for (int n = 0; n < 8; ++n){
        const int er = n * 16 + lr;
        bfr[n] = *reinterpret_cast<bf16x8*>(&s_wt[er * DIM + (k ^ ((er & 7) << 3))]);
      }
      #pragma unroll
      for (int i = 0; i < 2; ++i)
        #pragma unroll
        for (int n = 0; n < 8; ++n)
          acc[i][n] = __builtin_amdgcn_mfma_f32_16x16x32_bf16(af[i], bfr[n], acc[i][n], 0, 0, 0);
    }

    float bv[8];
    #pragma unroll
    for (int n = 0; n < 8; ++n) bv[n] = bias[n * 16 + lr];

    #pragma unroll
    for (int i = 0; i < 2; ++i){
      #pragma unroll
      for (int j = 0; j < 4; ++j){
        const int gr  = w * 32 + i * 16 + (l >> 4) * 4 + j;  // C/D: row=(l>>4)*4+reg, col=l&15
        const int m   = m0 + (gr >> 4);
        const int bct = gr & 15;
        float* po = out + ((size_t)bct * NTGT + m) * DIM;
        #pragma unroll
        for (int n = 0; n < 8; ++n) po[n * 16 + lr] = acc[i][n][j] + bv[n];
      }
    }
  }
}

extern "C" void kernel_launch(void* const* d_in, const int* in_sizes, int n_in,
                              void* d_out, int out_size, void* d_ws, size_t ws_size,
                              hipStream_t stream) {
  const float* x    = (const float*)d_in[0];
  const int*   pm   = (const int*)  d_in[1];
  const float* W    = (const float*)d_in[2];
  const float* bias = (const float*)d_in[3];
  float* out = (float*)d_out;

  int* counts  = (int*)d_ws;
  int* offsets = counts  + NTGT;
  int* cursor  = offsets + NTGT;
  int* child   = cursor  + NTGT;   // total ws use: 3*12288*4 + 49152*4 = 336 KB

  hipMemsetAsync(counts, 0, NTGT * sizeof(int), stream);
  k_hist   <<<NSRC/256, 256, 0, stream>>>(pm, counts);
  k_scan   <<<1, 1024, 0, stream>>>(counts, offsets, cursor);
  k_scatter<<<NSRC/256, 256, 0, stream>>>(pm, cursor, child);
  k_fused  <<<NTGT/MPER, 256, 0, stream>>>(x, W, bias, counts, offsets, child, out);
}